// Round 5
// baseline (347.555 us; speedup 1.0000x reference)
//
#include <hip/hip_runtime.h>

#define NN 200000   // nodes; D=128 features, 40 classes (padded to 48 in wt)
// grid: 3125 blocks x 64 rows = exactly NN -> no bounds checks anywhere

typedef __attribute__((ext_vector_type(8))) short bf16x8;
typedef __attribute__((ext_vector_type(4))) float f32x4;
typedef __attribute__((ext_vector_type(4))) unsigned int u32x4;

// round-to-nearest-even fp32 -> bf16 bits (prep kernel only)
static __device__ __forceinline__ short f2bf(float f) {
    unsigned u = __builtin_bit_cast(unsigned, f);
    u += 0x7fffu + ((u >> 16) & 1u);
    return (short)(u >> 16);
}

// pack 2 floats -> 2 bf16 in one u32 (round-half-up: add 0x8000, take hi16)
static __device__ __forceinline__ unsigned pk2(float a, float b) {
    unsigned ua = __builtin_bit_cast(unsigned, a) + 0x8000u;
    unsigned ub = __builtin_bit_cast(unsigned, b) + 0x8000u;
    return __builtin_amdgcn_perm(ub, ua, 0x07060302u);
}

// XOR-swizzled LDS offset for element (r, k) of a [16,128] bf16 tile.
// 8-elem (16B) chunks xored with r -> 2-way-max aliasing (free) on b128 reads.
static __device__ __forceinline__ int swz(int r, int k) {
    return (r << 7) + (((k >> 3) ^ r) << 3) + (k & 7);
}

// Pre-transpose + bf16-convert weights into workspace (elements):
// [0) Wt0[n][k]=W0[k][n] 128x128 | [16384) Wt1 | [32768) Wt2 | [49152) Wt3 48x128 (n>=40 zero)
__global__ void prep_weights_k(const float* __restrict__ W0, const float* __restrict__ W1,
                               const float* __restrict__ W2, const float* __restrict__ W3,
                               short* __restrict__ wt) {
    int e = blockIdx.x * 256 + threadIdx.x;   // 216 blocks * 256 = 55296
    if (e < 49152) {
        int l = e >> 14;
        int i = e & 16383;
        int n = i >> 7, k = i & 127;
        const float* W = (l == 0) ? W0 : ((l == 1) ? W1 : W2);
        wt[e] = f2bf(W[(k << 7) + n]);
    } else if (e < 55296) {
        int i = e - 49152;
        int n = i >> 7, k = i & 127;
        wt[e] = (n < 40) ? f2bf(W3[k * 40 + n]) : (short)0;
    }
}

// Fully fused 4-layer MLP + log_softmax. ZERO __syncthreads.
// 16 rows/wave (acc = 32 AGPR) so arch+acc regs fit the (256,4) 128-reg cap
// WITHOUT spilling -> 4 waves/SIMD. Activations in a per-wave-private 4KB LDS
// slice; weight B-fragments straight from global wt (L1/L2-hot, 108KB total).
__global__ __launch_bounds__(256, 4)
void mlp_fused_k(const float* __restrict__ x, const short* __restrict__ wt,
                 const float* __restrict__ b0, const float* __restrict__ b1,
                 const float* __restrict__ b2, const float* __restrict__ b3,
                 float* __restrict__ out) {
    __shared__ __align__(16) short sA[4][16 * 128];   // 16 KB total

    const int tid  = (int)threadIdx.x;
    const int lane = tid & 63;
    const int wv   = tid >> 6;       // wave 0..3
    const int m    = lane & 15;      // row (A) / col (B,C) within 16-tile
    const int quad = lane >> 4;      // 0..3
    short* sAw = &sA[wv][0];         // this wave's private activation slice
    const int grow0 = (int)blockIdx.x * 64 + wv * 16;   // first global row (exact fit)

    // per-lane weight fragment base: row (ct*16+m), k (ks*32+quad*8)
    const short* wb = wt + m * 128 + quad * 8;

    f32x4 acc[8];
    auto zacc = [&]() {
        #pragma unroll
        for (int ct = 0; ct < 8; ++ct)
            #pragma unroll
            for (int r = 0; r < 4; ++r) acc[ct][r] = 0.f;
    };

    // bias + SiLU + bf16 -> sAw (wave-private 16 rows), no barrier needed
    auto epilogue = [&](const float* __restrict__ bias) {
        float bv[8];
        #pragma unroll
        for (int ct = 0; ct < 8; ++ct) bv[ct] = bias[(ct << 4) + m];
        #pragma unroll
        for (int ct = 0; ct < 8; ++ct)
            #pragma unroll
            for (int r = 0; r < 4; ++r) {
                float v = acc[ct][r] + bv[ct];
                float h = v * __builtin_amdgcn_rcpf(1.f + __expf(-v));
                int rl = (quad << 2) + r;                // C/D: row = quad*4+reg
                unsigned u = __builtin_bit_cast(unsigned, h) + 0x8000u;
                sAw[swz(rl, (ct << 4) + m)] = (short)(u >> 16);
            }
    };

    // dense layer with A from the wave-private LDS slice, B from global
    auto dense = [&](int lbase) {
        zacc();
        #pragma unroll
        for (int ks = 0; ks < 4; ++ks) {
            int kk = (ks << 5) + (quad << 3);
            bf16x8 a0 = *(const bf16x8*)&sAw[swz(m, kk)];
            const short* wk = wb + lbase + (ks << 5);
            #pragma unroll
            for (int ct = 0; ct < 8; ++ct) {
                bf16x8 b = *(const bf16x8*)(wk + (ct << 11));
                acc[ct] = __builtin_amdgcn_mfma_f32_16x16x32_bf16(a0, b, acc[ct], 0, 0, 0);
            }
        }
    };

    // ---------------- layer 0: A straight from global x (packed cvt) ----
    zacc();
    {
        const f32x4* p0 = (const f32x4*)(x + ((long)(grow0 + m) << 7)) + quad * 2;
        #pragma unroll
        for (int ks = 0; ks < 4; ++ks) {
            f32x4 va = p0[ks * 8];
            f32x4 vb = p0[ks * 8 + 1];
            u32x4 ua;
            ua[0] = pk2(va[0], va[1]); ua[1] = pk2(va[2], va[3]);
            ua[2] = pk2(vb[0], vb[1]); ua[3] = pk2(vb[2], vb[3]);
            bf16x8 a0 = __builtin_bit_cast(bf16x8, ua);
            const short* wk = wb + (ks << 5);
            #pragma unroll
            for (int ct = 0; ct < 8; ++ct) {
                bf16x8 b = *(const bf16x8*)(wk + (ct << 11));
                acc[ct] = __builtin_amdgcn_mfma_f32_16x16x32_bf16(a0, b, acc[ct], 0, 0, 0);
            }
        }
    }
    epilogue(b0);

    // ---------------- layers 1, 2 ----------------
    dense(16384);
    epilogue(b1);
    dense(32768);
    epilogue(b2);

    // ---------------- layer 3 + log_softmax ----------------
    f32x4 c3[3];
    #pragma unroll
    for (int ct = 0; ct < 3; ++ct)
        #pragma unroll
        for (int r = 0; r < 4; ++r) c3[ct][r] = 0.f;
    #pragma unroll
    for (int ks = 0; ks < 4; ++ks) {
        int kk = (ks << 5) + (quad << 3);
        bf16x8 a0 = *(const bf16x8*)&sAw[swz(m, kk)];
        const short* wk = wb + 49152 + (ks << 5);
        #pragma unroll
        for (int ct = 0; ct < 3; ++ct) {
            bf16x8 b = *(const bf16x8*)(wk + (ct << 11));
            c3[ct] = __builtin_amdgcn_mfma_f32_16x16x32_bf16(a0, b, c3[ct], 0, 0, 0);
        }
    }
    const bool val2 = (m < 8);                    // cols 32..39 valid
    float bv0 = b3[m];
    float bv1 = b3[16 + m];
    float bv2 = val2 ? b3[32 + m] : 0.f;
    #pragma unroll
    for (int r = 0; r < 4; ++r) {
        float v0 = c3[0][r] + bv0;
        float v1 = c3[1][r] + bv1;
        float v2 = c3[2][r] + bv2;
        // node row lives on the 16 lanes of this quad-group; reduce cols 0..39
        float mx = fmaxf(v0, v1);
        mx = val2 ? fmaxf(mx, v2) : mx;
        #pragma unroll
        for (int s = 1; s < 16; s <<= 1)
            mx = fmaxf(mx, __shfl_xor(mx, s, 64));
        float sm = __expf(v0 - mx) + __expf(v1 - mx) + (val2 ? __expf(v2 - mx) : 0.f);
        #pragma unroll
        for (int s = 1; s < 16; s <<= 1)
            sm += __shfl_xor(sm, s, 64);
        float L = mx + __logf(sm);
        int grow = grow0 + (quad << 2) + r;        // C/D: row = quad*4+reg
        float* orow = out + (long)grow * 40;
        orow[m]      = v0 - L;
        orow[16 + m] = v1 - L;
        if (val2) orow[32 + m] = v2 - L;
    }
}

extern "C" void kernel_launch(void* const* d_in, const int* in_sizes, int n_in,
                              void* d_out, int out_size, void* d_ws, size_t ws_size,
                              hipStream_t stream) {
    const float* x   = (const float*)d_in[0];
    // d_in[1] = edge_index (unused: ChebConv K=1 ignores the Laplacian)
    const float* W0  = (const float*)d_in[2];
    const float* bb0 = (const float*)d_in[3];
    const float* W1  = (const float*)d_in[4];
    const float* bb1 = (const float*)d_in[5];
    const float* W2  = (const float*)d_in[6];
    const float* bb2 = (const float*)d_in[7];
    const float* W3  = (const float*)d_in[8];
    const float* bb3 = (const float*)d_in[9];
    short* wt  = (short*)d_ws;         // 110592 B of bf16 transposed weights
    float* out = (float*)d_out;

    hipLaunchKernelGGL(prep_weights_k, dim3(216), dim3(256), 0, stream, W0, W1, W2, W3, wt);
    hipLaunchKernelGGL(mlp_fused_k, dim3(NN / 64), dim3(256), 0, stream,
                       x, wt, bb0, bb1, bb2, bb3, out);
}

// Round 6
// 230.433 us; speedup vs baseline: 1.5083x; 1.5083x over previous
//
#include <hip/hip_runtime.h>

#define NN 200000      // nodes; D=128 features, 40 classes (padded to 48 in wt)
#define NW 12          // waves per block
#define NBLK 256       // persistent blocks (1 per CU; LDS pins 1 block/CU)
#define NT 12500       // tiles of 16 rows: 12500*16 = NN exactly
#define WSTRIDE (NBLK * NW)   // 3072 global waves

typedef __attribute__((ext_vector_type(8))) short bf16x8;
typedef __attribute__((ext_vector_type(4))) float f32x4;
typedef __attribute__((ext_vector_type(4))) unsigned int u32x4;

// round-to-nearest-even fp32 -> bf16 bits (prep kernel only)
static __device__ __forceinline__ short f2bf(float f) {
    unsigned u = __builtin_bit_cast(unsigned, f);
    u += 0x7fffu + ((u >> 16) & 1u);
    return (short)(u >> 16);
}

// pack 2 floats -> 2 bf16 in one u32 (round-half-up)
static __device__ __forceinline__ unsigned pk2(float a, float b) {
    unsigned ua = __builtin_bit_cast(unsigned, a) + 0x8000u;
    unsigned ub = __builtin_bit_cast(unsigned, b) + 0x8000u;
    return __builtin_amdgcn_perm(ub, ua, 0x07060302u);
}

// XOR-swizzled LDS offset for element (r, k) of a [*,128] bf16 table.
// 16B chunks xored with (r&15) -> conflict-free ds_read_b128 fragments.
static __device__ __forceinline__ int swz(int r, int k) {
    return (r << 7) + (((k >> 3) ^ (r & 15)) << 3) + (k & 7);
}

// Pre-transpose + bf16-convert weights into workspace (elements):
// [0) Wt0[n][k]=W0[k][n] 128x128 | [16384) Wt1 | [32768) Wt2 | [49152) Wt3 48x128 (n>=40 zero)
__global__ void prep_weights_k(const float* __restrict__ W0, const float* __restrict__ W1,
                               const float* __restrict__ W2, const float* __restrict__ W3,
                               short* __restrict__ wt) {
    int e = blockIdx.x * 256 + threadIdx.x;   // 216 blocks * 256 = 55296
    if (e < 49152) {
        int l = e >> 14;
        int i = e & 16383;
        int n = i >> 7, k = i & 127;
        const float* W = (l == 0) ? W0 : ((l == 1) ? W1 : W2);
        wt[e] = f2bf(W[(k << 7) + n]);
    } else if (e < 55296) {
        int i = e - 49152;
        int n = i >> 7, k = i & 127;
        wt[e] = (n < 40) ? f2bf(W3[k * 40 + n]) : (short)0;
    }
}

// Persistent fused 4-layer MLP + log_softmax.
//  - ALL weights (108KB bf16, swizzled) staged into LDS ONCE per block,
//    then ONE barrier; afterwards waves are fully independent.
//  - each wave grid-strides over 16-row tiles; x prefetched one tile deep.
//  - activations round-trip a per-wave-private 4KB LDS slice.
// LDS total = 110592 + 49152 = 159744 B <= 163840 (gfx950) -> 1 block/CU, 12 waves.
__global__ __launch_bounds__(768)
void mlp_fused_k(const float* __restrict__ x, const short* __restrict__ wt,
                 const float* __restrict__ b0, const float* __restrict__ b1,
                 const float* __restrict__ b2, const float* __restrict__ b3,
                 float* __restrict__ out) {
    __shared__ __align__(16) short sW[55296];       // all 4 layers, swizzled
    __shared__ __align__(16) short sA[NW][2048];    // per-wave activation slices

    const int tid  = (int)threadIdx.x;
    const int lane = tid & 63;
    const int wv   = tid >> 6;       // wave 0..11
    const int m    = lane & 15;      // row (A) / col (B,C) within 16-tile
    const int quad = lane >> 4;      // 0..3
    short* sAw = &sA[wv][0];

    // ---- stage ALL weights global->LDS (swizzled), 6912 16B chunks = 9*768 ----
    {
        const u32x4* src = (const u32x4*)wt;
        #pragma unroll
        for (int i = 0; i < 9; ++i) {
            int q = tid + i * 768;             // exactly 6912 total, no tail
            int R = q >> 4, c = q & 15;
            *(u32x4*)&sW[(R << 7) + ((c ^ (R & 15)) << 3)] = src[q];
        }
    }
    __syncthreads();   // the ONLY barrier

    // ---- hoist biases (tile-invariant, per-lane) ----
    float bv0[8], bv1[8], bv2[8];
    #pragma unroll
    for (int ct = 0; ct < 8; ++ct) {
        bv0[ct] = b0[(ct << 4) + m];
        bv1[ct] = b1[(ct << 4) + m];
        bv2[ct] = b2[(ct << 4) + m];
    }
    const bool val2 = (m < 8);
    float b3v0 = b3[m], b3v1 = b3[16 + m], b3v2 = val2 ? b3[32 + m] : 0.f;

    f32x4 acc[8];
    auto zacc = [&]() {
        #pragma unroll
        for (int ct = 0; ct < 8; ++ct)
            #pragma unroll
            for (int r = 0; r < 4; ++r) acc[ct][r] = 0.f;
    };

    // bias + SiLU + bf16 -> sAw (wave-private 16 rows)
    auto epilogue = [&](const float* bv) {
        #pragma unroll
        for (int ct = 0; ct < 8; ++ct)
            #pragma unroll
            for (int r = 0; r < 4; ++r) {
                float v = acc[ct][r] + bv[ct];
                float h = v * __builtin_amdgcn_rcpf(1.f + __expf(-v));
                int rl = (quad << 2) + r;                // C/D: row = quad*4+reg
                unsigned u = __builtin_bit_cast(unsigned, h) + 0x8000u;
                sAw[swz(rl, (ct << 4) + m)] = (short)(u >> 16);
            }
    };

    // dense layer: A from wave-private slice, B from resident sW
    auto dense = [&](int lbase) {
        zacc();
        #pragma unroll
        for (int ks = 0; ks < 4; ++ks) {
            int kk = (ks << 5) + (quad << 3);
            bf16x8 a0 = *(const bf16x8*)&sAw[swz(m, kk)];
            #pragma unroll
            for (int ct = 0; ct < 8; ++ct) {
                bf16x8 b = *(const bf16x8*)&sW[lbase + swz((ct << 4) + m, kk)];
                acc[ct] = __builtin_amdgcn_mfma_f32_16x16x32_bf16(a0, b, acc[ct], 0, 0, 0);
            }
        }
    };

    // ---- persistent tile loop with one-deep x prefetch ----
    int t = (int)blockIdx.x * NW + wv;       // first tile for this wave (< WSTRIDE <= NT)
    f32x4 xc[8];
    {
        const f32x4* p = (const f32x4*)(x + ((long)(t * 16 + m) << 7)) + quad * 2;
        #pragma unroll
        for (int ks = 0; ks < 4; ++ks) { xc[ks * 2] = p[ks * 8]; xc[ks * 2 + 1] = p[ks * 8 + 1]; }
    }

    while (true) {
        int tn = t + WSTRIDE;
        bool has = tn < NT;                   // wave-uniform
        f32x4 xn[8];
        if (has) {
            const f32x4* p = (const f32x4*)(x + ((long)(tn * 16 + m) << 7)) + quad * 2;
            #pragma unroll
            for (int ks = 0; ks < 4; ++ks) { xn[ks * 2] = p[ks * 8]; xn[ks * 2 + 1] = p[ks * 8 + 1]; }
        }

        // layer 0: A from prefetched regs
        zacc();
        #pragma unroll
        for (int ks = 0; ks < 4; ++ks) {
            f32x4 va = xc[ks * 2], vb = xc[ks * 2 + 1];
            u32x4 ua;
            ua[0] = pk2(va[0], va[1]); ua[1] = pk2(va[2], va[3]);
            ua[2] = pk2(vb[0], vb[1]); ua[3] = pk2(vb[2], vb[3]);
            bf16x8 a0 = __builtin_bit_cast(bf16x8, ua);
            int kk = (ks << 5) + (quad << 3);
            #pragma unroll
            for (int ct = 0; ct < 8; ++ct) {
                bf16x8 b = *(const bf16x8*)&sW[swz((ct << 4) + m, kk)];
                acc[ct] = __builtin_amdgcn_mfma_f32_16x16x32_bf16(a0, b, acc[ct], 0, 0, 0);
            }
        }
        epilogue(bv0);
        dense(16384);
        epilogue(bv1);
        dense(32768);
        epilogue(bv2);

        // layer 3 (48 padded cols) + log_softmax
        f32x4 c3[3];
        #pragma unroll
        for (int ct = 0; ct < 3; ++ct)
            #pragma unroll
            for (int r = 0; r < 4; ++r) c3[ct][r] = 0.f;
        #pragma unroll
        for (int ks = 0; ks < 4; ++ks) {
            int kk = (ks << 5) + (quad << 3);
            bf16x8 a0 = *(const bf16x8*)&sAw[swz(m, kk)];
            #pragma unroll
            for (int ct = 0; ct < 3; ++ct) {
                bf16x8 b = *(const bf16x8*)&sW[49152 + swz((ct << 4) + m, kk)];
                c3[ct] = __builtin_amdgcn_mfma_f32_16x16x32_bf16(a0, b, c3[ct], 0, 0, 0);
            }
        }
        #pragma unroll
        for (int r = 0; r < 4; ++r) {
            float v0 = c3[0][r] + b3v0;
            float v1 = c3[1][r] + b3v1;
            float v2 = c3[2][r] + b3v2;
            float mx = fmaxf(v0, v1);
            mx = val2 ? fmaxf(mx, v2) : mx;
            #pragma unroll
            for (int s = 1; s < 16; s <<= 1)
                mx = fmaxf(mx, __shfl_xor(mx, s, 64));
            float sm = __expf(v0 - mx) + __expf(v1 - mx) + (val2 ? __expf(v2 - mx) : 0.f);
            #pragma unroll
            for (int s = 1; s < 16; s <<= 1)
                sm += __shfl_xor(sm, s, 64);
            float L = mx + __logf(sm);
            int grow = t * 16 + (quad << 2) + r;   // C/D: row = quad*4+reg
            float* orow = out + (long)grow * 40;
            orow[m]      = v0 - L;
            orow[16 + m] = v1 - L;
            if (val2) orow[32 + m] = v2 - L;
        }

        if (!has) break;
        #pragma unroll
        for (int i = 0; i < 8; ++i) xc[i] = xn[i];
        t = tn;
    }
}

extern "C" void kernel_launch(void* const* d_in, const int* in_sizes, int n_in,
                              void* d_out, int out_size, void* d_ws, size_t ws_size,
                              hipStream_t stream) {
    const float* x   = (const float*)d_in[0];
    // d_in[1] = edge_index (unused: ChebConv K=1 ignores the Laplacian)
    const float* W0  = (const float*)d_in[2];
    const float* bb0 = (const float*)d_in[3];
    const float* W1  = (const float*)d_in[4];
    const float* bb1 = (const float*)d_in[5];
    const float* W2  = (const float*)d_in[6];
    const float* bb2 = (const float*)d_in[7];
    const float* W3  = (const float*)d_in[8];
    const float* bb3 = (const float*)d_in[9];
    short* wt  = (short*)d_ws;         // 110592 B of bf16 transposed weights
    float* out = (float*)d_out;

    hipLaunchKernelGGL(prep_weights_k, dim3(216), dim3(256), 0, stream, W0, W1, W2, W3, wt);
    hipLaunchKernelGGL(mlp_fused_k, dim3(NBLK), dim3(768), 0, stream,
                       x, wt, bb0, bb1, bb2, bb3, out);
}